// Round 5
// baseline (798.217 us; speedup 1.0000x reference)
//
#include <hip/hip_runtime.h>
#include <math.h>

#define Hh 720
#define Ww 1280
#define Bb 2
#define HW (Hh*Ww)
#define OUTC 18
#define EPSF 1e-7f

// Marching-strip splat geometry. A source with |dx|,|dy| <= DMAX=2 has corner
// offsets in [-2,+3] (proven R4 bound). Strip = 64 cols x 90 rows per block,
// marched in 15-row steps with a 20-row LDS ring. Cells within +-2 of a
// segment/strip boundary are shared across blocks -> atomicAdd; all other
// cells are exclusively owned -> plain store.
#define DMAX 2.0f
#define TW 64
#define SEG 90
#define TH 15
#define ITERS (SEG/TH)    // 6
#define WIN (TH+5)        // 20-row ring
#define LW (TW+5)         // 69 cols

__global__ __launch_bounds__(256) void splat_strip_kernel(
    const float* __restrict__ img0, const float* __restrict__ img1,
    const float* __restrict__ flow0, const float* __restrict__ flow1,
    const float* __restrict__ z0, const float* __restrict__ z1,
    float* __restrict__ out)
{
    __shared__ float acc[2][4][WIN][LW];   // [dir][v0,v1,v2,w][row ring][col]

    const int X0  = blockIdx.x * TW;
    const int S0  = blockIdx.y * SEG;
    const int b   = blockIdx.z;
    const int tid = threadIdx.x;

    // zero the whole ring window
    float* af = &acc[0][0][0][0];
    for (int c = tid; c < 2 * 4 * WIN * LW; c += 256) af[c] = 0.0f;

    for (int it = 0; it < ITERS; ++it) {
        const int Y0 = S0 + it * TH;
        __syncthreads();   // prior flush+zero (or init) complete

        // ---- stage: splat this 64x15 source block into the LDS ring ----
        for (int c = tid; c < TW * TH; c += 256) {
            const int sy = Y0 + c / TW;
            const int sx = X0 + (c % TW);
            const int p  = sy * Ww + sx;
#pragma unroll
            for (int d = 0; d < 2; ++d) {
                const float* img = d ? img1 : img0;
                const float* flw = d ? flow0 : flow1;
                const float* met = d ? z0 : z1;

                float dx = 0.5f * flw[((size_t)b * 2 + 1) * HW + p];  // x-disp = flow ch1
                float dy = 0.5f * flw[((size_t)b * 2 + 0) * HW + p];  // y-disp = flow ch0
                if (!(fabsf(dx) <= DMAX && fabsf(dy) <= DMAX)) continue;  // fallback kernel

                float fx = (float)sx + dx;
                float fy = (float)sy + dy;
                float w  = expf(met[(size_t)b * HW + p]);
                float v0 = img[((size_t)b * 3 + 0) * HW + p] * w;
                float v1 = img[((size_t)b * 3 + 1) * HW + p] * w;
                float v2 = img[((size_t)b * 3 + 2) * HW + p] * w;

                float x0f = floorf(fx), y0f = floorf(fy);
                float x1f = x0f + 1.0f, y1f = y0f + 1.0f;
                int   x0  = (int)x0f,  y0i = (int)y0f;
                float wxs[2] = { x1f - fx, fx - x0f };
                float wys[2] = { y1f - fy, fy - y0f };

#pragma unroll
                for (int cy = 0; cy < 2; ++cy) {
                    int yy = y0i + cy;
                    if (yy < 0 || yy >= Hh) continue;
#pragma unroll
                    for (int cx = 0; cx < 2; ++cx) {
                        int xx = x0 + cx;
                        if (xx < 0 || xx >= Ww) continue;
                        float wt = wxs[cx] * wys[cy];
                        if (wt == 0.0f) continue;
                        int sl = yy % WIN;           // ring slot (20 consecutive rows -> bijective)
                        int l  = xx - X0 + 2;        // in [0, 68]
                        atomicAdd(&acc[d][0][sl][l], v0 * wt);
                        atomicAdd(&acc[d][1][sl][l], v1 * wt);
                        atomicAdd(&acc[d][2][sl][l], v2 * wt);
                        atomicAdd(&acc[d][3][sl][l], w  * wt);
                    }
                }
            }
        }
        __syncthreads();   // staging complete before flush reads

        // ---- flush rows Y0-2 .. Y0+TH-3 (final: future sources write >= Y0+TH-2) ----
        for (int c = tid; c < TH * LW; c += 256) {
            const int rr = Y0 - 2 + c / LW;
            const int l  = c % LW;
            const int cc = X0 - 2 + l;
            if (rr < 0 || cc < 0 || cc >= Ww) continue;   // rr < Hh guaranteed (max S0+87)
            const int sl = rr % WIN;
            const bool shared = (((rr + 2) % SEG) <= 4) || (((cc + 2) % TW) <= 4);
            const size_t q = (size_t)rr * Ww + cc;
#pragma unroll
            for (int d = 0; d < 2; ++d) {
                float ws = acc[d][3][sl][l];
                if (ws != 0.0f) {
                    float* aI = out + ((size_t)b * OUTC + (d ? 9 : 6)) * HW;
                    float* aW = out + ((size_t)b * OUTC + (d ? 17 : 16)) * HW;
                    if (shared) {
                        atomicAdd(aI + q,          acc[d][0][sl][l]);
                        atomicAdd(aI + HW + q,     acc[d][1][sl][l]);
                        atomicAdd(aI + 2 * HW + q, acc[d][2][sl][l]);
                        atomicAdd(aW + q,          ws);
                    } else {
                        aI[q]          = acc[d][0][sl][l];
                        aI[HW + q]     = acc[d][1][sl][l];
                        aI[2 * HW + q] = acc[d][2][sl][l];
                        aW[q]          = ws;
                    }
                }
                acc[d][0][sl][l] = 0.0f;   // recycle slot for ring reuse
                acc[d][1][sl][l] = 0.0f;
                acc[d][2][sl][l] = 0.0f;
                acc[d][3][sl][l] = 0.0f;
            }
        }
    }
    __syncthreads();

    // ---- epilogue: rows S0+SEG-2 .. S0+SEG+2 (always row-shared -> atomic) ----
    for (int c = tid; c < 5 * LW; c += 256) {
        const int rr = S0 + SEG - 2 + c / LW;
        const int l  = c % LW;
        const int cc = X0 - 2 + l;
        if (rr >= Hh || cc < 0 || cc >= Ww) continue;
        const int sl = rr % WIN;
        const size_t q = (size_t)rr * Ww + cc;
#pragma unroll
        for (int d = 0; d < 2; ++d) {
            float ws = acc[d][3][sl][l];
            if (ws != 0.0f) {
                float* aI = out + ((size_t)b * OUTC + (d ? 9 : 6)) * HW;
                float* aW = out + ((size_t)b * OUTC + (d ? 17 : 16)) * HW;
                atomicAdd(aI + q,          acc[d][0][sl][l]);
                atomicAdd(aI + HW + q,     acc[d][1][sl][l]);
                atomicAdd(aI + 2 * HW + q, acc[d][2][sl][l]);
                atomicAdd(aW + q,          ws);
            }
        }
    }
}

// ---------------------------------------------------------------------------
// Fallback: atomic scatter for the rare |d|>DMAX sources (runs after splat;
// identical float routing expression -> exactly complementary).
// ---------------------------------------------------------------------------
__global__ __launch_bounds__(256) void fallback_kernel(
    const float* __restrict__ img0, const float* __restrict__ img1,
    const float* __restrict__ flow0, const float* __restrict__ flow1,
    const float* __restrict__ z0, const float* __restrict__ z1,
    float* __restrict__ out)
{
    int i = blockIdx.x * 256 + threadIdx.x;
    if (i >= Bb * HW) return;
    int b = i / HW;
    int p = i - b * HW;
    int y = p / Ww;
    int x = p - y * Ww;

#pragma unroll
    for (int d = 0; d < 2; ++d) {
        const float* flw = d ? flow0 : flow1;
        float dx = 0.5f * flw[((size_t)b * 2 + 1) * HW + p];
        float dy = 0.5f * flw[((size_t)b * 2 + 0) * HW + p];
        if (fabsf(dx) <= DMAX && fabsf(dy) <= DMAX) continue;  // splat did it

        const float* img = d ? img1 : img0;
        const float* met = d ? z0 : z1;
        float* accImg = out + ((size_t)b * OUTC + (d ? 9 : 6)) * HW;
        float* accW   = out + ((size_t)b * OUTC + (d ? 17 : 16)) * HW;

        float fx = (float)x + dx;
        float fy = (float)y + dy;
        float w  = expf(met[(size_t)b * HW + p]);
        float v0 = img[((size_t)b * 3 + 0) * HW + p] * w;
        float v1 = img[((size_t)b * 3 + 1) * HW + p] * w;
        float v2 = img[((size_t)b * 3 + 2) * HW + p] * w;

        float x0f = floorf(fx), y0f = floorf(fy);
        float x1f = x0f + 1.0f, y1f = y0f + 1.0f;
        int   x0  = (int)x0f,  y0i = (int)y0f;
        float wxs[2] = { x1f - fx, fx - x0f };
        float wys[2] = { y1f - fy, fy - y0f };

#pragma unroll
        for (int cy = 0; cy < 2; ++cy) {
            int yy = y0i + cy;
            if (yy < 0 || yy >= Hh) continue;
#pragma unroll
            for (int cx = 0; cx < 2; ++cx) {
                int xx = x0 + cx;
                if (xx < 0 || xx >= Ww) continue;
                float wt = wxs[cx] * wys[cy];
                if (wt == 0.0f) continue;
                int q = yy * Ww + xx;
                atomicAdd(accImg + q,          v0 * wt);
                atomicAdd(accImg + HW + q,     v1 * wt);
                atomicAdd(accImg + 2 * HW + q, v2 * wt);
                atomicAdd(accW + q,            w  * wt);
            }
        }
    }
}

// ---------------------------------------------------------------------------
// R1-proven full-2D erosion of raw weight sums: ch16/17 -> ch12/13.
// morph_open(s/(s+eps)) == f(morph_open(s)) since x/(x+eps) is monotone.
// ---------------------------------------------------------------------------
__global__ __launch_bounds__(256) void erode_kernel(float* __restrict__ out,
                                                    const int* __restrict__ kptr)
{
    int i = blockIdx.x * 256 + threadIdx.x;
    if (i >= Bb * HW) return;
    int b = i / HW;
    int p = i - b * HW;
    int y = p / Ww;
    int x = p - y * Ww;
    int k = *kptr;

    const float* s01 = out + ((size_t)b * OUTC + 16) * HW;
    const float* s10 = out + ((size_t)b * OUTC + 17) * HW;
    float* er01 = out + ((size_t)b * OUTC + 12) * HW;
    float* er10 = out + ((size_t)b * OUTC + 13) * HW;

    if (k <= 0) { er01[p] = s01[p]; er10[p] = s10[p]; return; }

    int lo = (k - 1) / 2, hi = (k - 1) - lo;
    float m0 = INFINITY, m1 = INFINITY;
    for (int dy = -lo; dy <= hi; ++dy) {
        int yy = y + dy;
        if (yy < 0 || yy >= Hh) continue;
        for (int dx = -lo; dx <= hi; ++dx) {
            int xx = x + dx;
            if (xx < 0 || xx >= Ww) continue;
            int q = yy * Ww + xx;
            m0 = fminf(m0, s01[q]);
            m1 = fminf(m1, s10[q]);
        }
    }
    er01[p] = m0;
    er10[p] = m1;
}

// ---------------------------------------------------------------------------
// R1-proven fuse: full-2D dilation of ch12/13 -> opened weight sum; mask =
// o/(o+eps); normalize numerators; blend. Writes ch0..11, 16, 17 only.
// ---------------------------------------------------------------------------
__global__ __launch_bounds__(256) void fuse_kernel(float* __restrict__ out,
                                                   const int* __restrict__ kptr)
{
    int i = blockIdx.x * 256 + threadIdx.x;
    if (i >= Bb * HW) return;
    int b = i / HW;
    int p = i - b * HW;
    int y = p / Ww;
    int x = p - y * Ww;
    int k = *kptr;

    const float* er01 = out + ((size_t)b * OUTC + 12) * HW;
    const float* er10 = out + ((size_t)b * OUTC + 13) * HW;

    float o0, o1;
    if (k <= 0) {
        o0 = er01[p];
        o1 = er10[p];
    } else {
        int lo = (k - 1) / 2, hi = (k - 1) - lo;
        o0 = -INFINITY; o1 = -INFINITY;
        for (int dy = -lo; dy <= hi; ++dy) {
            int yy = y + dy;
            if (yy < 0 || yy >= Hh) continue;
            for (int dx = -lo; dx <= hi; ++dx) {
                int xx = x + dx;
                if (xx < 0 || xx >= Ww) continue;
                int q = yy * Ww + xx;
                o0 = fmaxf(o0, er01[q]);
                o1 = fmaxf(o1, er10[q]);
            }
        }
    }

    float m01 = o0 / (o0 + EPSF);
    float m10 = o1 / (o1 + EPSF);

    float* ob = out + (size_t)b * OUTC * HW;
    float s01 = ob[(size_t)16 * HW + p];
    float s10 = ob[(size_t)17 * HW + p];
    float d01 = s01 + EPSF;
    float d10 = s10 + EPSF;

#pragma unroll
    for (int c = 0; c < 3; ++c) {
        float f01i = ob[((size_t)6 + c) * HW + p] / d01;
        float f10i = ob[((size_t)9 + c) * HW + p] / d10;
        float base0 = m01 * f01i + (1.0f - m01) * f10i;
        float base1 = m10 * f10i + (1.0f - m10) * f01i;
        ob[((size_t)0 + c) * HW + p] = base0;
        ob[((size_t)3 + c) * HW + p] = base1;
        ob[((size_t)6 + c) * HW + p] = f01i;
        ob[((size_t)9 + c) * HW + p] = f10i;
    }
    ob[(size_t)16 * HW + p] = m01;
    ob[(size_t)17 * HW + p] = m10;
}

// ---------------------------------------------------------------------------
// Write scaled flows into ch12..15 (overwrites the parked erosions). Last.
// ---------------------------------------------------------------------------
__global__ __launch_bounds__(256) void flow_kernel(const float* __restrict__ flow0,
                                                   const float* __restrict__ flow1,
                                                   float* __restrict__ out)
{
    int i = blockIdx.x * 256 + threadIdx.x;
    if (i >= Bb * 4 * HW) return;
    int b = i / (4 * HW);
    int r = i - b * 4 * HW;
    int c = r / HW;
    int p = r - c * HW;
    float v = (c < 2) ? 0.5f * flow0[((size_t)b * 2 + c) * HW + p]
                      : 0.5f * flow1[((size_t)b * 2 + (c - 2)) * HW + p];
    out[((size_t)b * OUTC + 12 + c) * HW + p] = v;
}

extern "C" void kernel_launch(void* const* d_in, const int* in_sizes, int n_in,
                              void* d_out, int out_size, void* d_ws, size_t ws_size,
                              hipStream_t stream) {
    const float* img0  = (const float*)d_in[0];
    const float* img1  = (const float*)d_in[1];
    const float* flow0 = (const float*)d_in[2];
    const float* flow1 = (const float*)d_in[3];
    const float* z0    = (const float*)d_in[4];
    const float* z1    = (const float*)d_in[5];
    const int*   kptr  = (const int*)d_in[6];
    float* out = (float*)d_out;

    // zero the 8 accumulator planes (seam atomics + fallback add onto zeros)
    for (int b = 0; b < Bb; ++b) {
        hipMemsetAsync(out + ((size_t)b * OUTC + 6) * HW, 0, (size_t)6 * HW * sizeof(float), stream);
        hipMemsetAsync(out + ((size_t)b * OUTC + 16) * HW, 0, (size_t)2 * HW * sizeof(float), stream);
    }

    int n = Bb * HW;
    int blocks = (n + 255) / 256;

    dim3 sgrid(Ww / TW, Hh / SEG, Bb);   // 20 x 8 x 2 = 320 blocks
    splat_strip_kernel<<<sgrid, 256, 0, stream>>>(img0, img1, flow0, flow1, z0, z1, out);
    fallback_kernel<<<blocks, 256, 0, stream>>>(img0, img1, flow0, flow1, z0, z1, out);
    erode_kernel<<<blocks, 256, 0, stream>>>(out, kptr);
    fuse_kernel<<<blocks, 256, 0, stream>>>(out, kptr);
    int n4 = Bb * 4 * HW;
    flow_kernel<<<(n4 + 255) / 256, 256, 0, stream>>>(flow0, flow1, out);
}